// Round 11
// baseline (98.585 us; speedup 1.0000x reference)
//
#include <hip/hip_runtime.h>
#include <hip/hip_bf16.h>

#define BATCH 8
#define NN 2048
#define FIN 128
#define FOUT 64
#define ROWS_TOTAL (BATCH * NN)           // 16384
#define K0_BLOCKS 2048                    // mask part (dispatched first)
#define K1_BLOCKS 512                     // projection part
#define K0_THREADS (K0_BLOCKS * 256)      // 524288

typedef __attribute__((ext_vector_type(8))) short bf16x8;
typedef __attribute__((ext_vector_type(4))) float f32x4;
typedef __attribute__((ext_vector_type(8))) short short8;

__device__ inline short f2bf(float x) {
    __hip_bfloat16 b = __float2bfloat16(x);   // RNE
    short s;
    __builtin_memcpy(&s, &b, 2);
    return s;
}

// ---------------------------------------------------------------------------
// K01: adj->bitmask (blocks [0,2048)) + projection (rest).
// k0: 16 slots; slot it loads adj4[it*524288 + T] -> every wave instruction
// is a DENSE 1 KB span (64 lanes x contiguous 16 B) -> minimal line-requests;
// all 16 issued before any use. Lane pair (t, t^1) holds one octet's two
// halves; combine nibbles via shfl_xor(1); even lane stores the byte.
// k1 body byte-identical to validated rounds 1..10.
// ---------------------------------------------------------------------------
__global__ __launch_bounds__(256) void k01(
        const float* __restrict__ h, const float* __restrict__ W,
        const float* __restrict__ a, const float* __restrict__ adj,
        short* __restrict__ whT, float* __restrict__ wh1, float* __restrict__ wh2,
        unsigned char* __restrict__ maskb) {
    const int tid  = threadIdx.x;
    const int lane = tid & 63;
    const int wid  = tid >> 6;

    if (blockIdx.x < K0_BLOCKS) {
        // ---------------- k0: adj -> bitmask, dense-per-inst deep stream ----------------
        const int T = blockIdx.x * 256 + tid;   // 0..524287
        const f32x4* adj4 = (const f32x4*)adj;

        f32x4 v[16];
        #pragma unroll
        for (int it = 0; it < 16; ++it)
            v[it] = adj4[(size_t)it * K0_THREADS + T];
        __builtin_amdgcn_sched_barrier(0);   // all 16 loads issued before any use

        #pragma unroll
        for (int it = 0; it < 16; ++it) {
            unsigned int nib =
                (v[it][0] == 0.f ? 1u : 0u) | (v[it][1] == 0.f ? 2u : 0u) |
                (v[it][2] == 0.f ? 4u : 0u) | (v[it][3] == 0.f ? 8u : 0u);
            unsigned int other = (unsigned int)__shfl_xor((int)nib, 1, 64);
            if (!(lane & 1)) {
                const size_t q = (size_t)it * K0_THREADS + T;   // float4 index (even)
                maskb[q >> 1] = (unsigned char)(nib | (other << 4));
            }
        }
    } else {
        // ---------------- k1: wh = h @ W, whT bf16, wh1/wh2 ----------------
        const int gw   = (blockIdx.x - K0_BLOCKS) * 4 + wid;
        const int row0 = gw * 8;
        const int b    = row0 >> 11;
        const int rloc = row0 & (NN - 1);

        float acc[8] = {0.f,0.f,0.f,0.f,0.f,0.f,0.f,0.f};
        const float* hrow = h + (size_t)row0 * FIN;

        #pragma unroll 2
        for (int kc = 0; kc < FIN / 4; ++kc) {
            float wv0 = W[(4*kc + 0) * FOUT + lane];
            float wv1 = W[(4*kc + 1) * FOUT + lane];
            float wv2 = W[(4*kc + 2) * FOUT + lane];
            float wv3 = W[(4*kc + 3) * FOUT + lane];
            #pragma unroll
            for (int r = 0; r < 8; ++r) {
                float4 h4 = *(const float4*)(hrow + r * FIN + 4*kc);
                acc[r] = fmaf(h4.x, wv0, acc[r]);
                acc[r] = fmaf(h4.y, wv1, acc[r]);
                acc[r] = fmaf(h4.z, wv2, acc[r]);
                acc[r] = fmaf(h4.w, wv3, acc[r]);
            }
        }

        short8 st;
        #pragma unroll
        for (int r = 0; r < 8; ++r) st[r] = f2bf(acc[r]);
        *(short8*)(whT + ((size_t)b * FOUT + lane) * NN + rloc) = st;

        const float a1 = a[lane];
        const float a2 = a[FOUT + lane];
        #pragma unroll
        for (int r = 0; r < 8; ++r) {
            const int row = row0 + r;
            float v1 = acc[r] * a1;
            float v2 = acc[r] * a2;
            #pragma unroll
            for (int m = 32; m >= 1; m >>= 1) {
                v1 += __shfl_xor(v1, m, 64);
                v2 += __shfl_xor(v2, m, 64);
            }
            if (lane == 0) { wh1[row] = v1; wh2[row] = v2; }
        }
    }
}

// ---------------------------------------------------------------------------
// K2 v5 (byte-identical to validated round 9 core): mask-driven fused
// softmax+PV via MFMA, layout-self-calibrated. No adj stream, no in-loop
// barriers. 16 rows x 8 waves; wave w owns j = cn*256 + w*32 + [0,32).
// ---------------------------------------------------------------------------
__global__ __launch_bounds__(512) void k2_attn(
        const unsigned long long* __restrict__ maskg, const short* __restrict__ whT,
        const float* __restrict__ wh1, const float* __restrict__ wh2,
        float* __restrict__ out) {
    __shared__ unsigned long long lds_mask64[512];   // 4 KB: [16 rows][32 words]
    __shared__ float lds_acc[8][16][FOUT];           // 32 KB
    __shared__ float lds_l[8][16];

    const int tid  = threadIdx.x;
    const int lane = tid & 63;
    const int w    = tid >> 6;               // 0..7
    const int row0 = blockIdx.x * 16;
    const int b    = row0 >> 11;
    const int iloc = lane & 15;
    const int kg   = lane >> 4;              // 0..3

    const float* wh2b = wh2 + b * NN;
    const short* whTb = whT + (size_t)b * FOUT * NN;
    const float  wh1v = wh1[row0 + iloc];

    // mask preload: rows row0..row0+15 = 512 uint64, one per thread
    lds_mask64[tid] = maskg[(size_t)row0 * 32 + tid];

    // --- layout self-calibration (proven round 3) ---
    bf16x8 onesf, idxf;
    #pragma unroll
    for (int e = 0; e < 8; ++e) { onesf[e] = (short)0x3F80; idxf[e] = f2bf((float)iloc); }
    f32x4 rowM = {}, colM = {};
    rowM = __builtin_amdgcn_mfma_f32_16x16x32_bf16(idxf, onesf, rowM, 0, 0, 0);
    colM = __builtin_amdgcn_mfma_f32_16x16x32_bf16(onesf, idxf, colM, 0, 0, 0);
    int rmap[4], cmap[4];
    #pragma unroll
    for (int reg = 0; reg < 4; ++reg) {
        int r = (int)(rowM[reg] * 0.03125f + 0.5f);
        int c = (int)(colM[reg] * 0.03125f + 0.5f);
        rmap[reg] = min(max(r, 0), 15);
        cmap[reg] = min(max(c, 0), 15);
    }

    __syncthreads();   // mask ready
    const unsigned char* mb8 = (const unsigned char*)lds_mask64;

    f32x4 acc[4] = {};
    f32x4 accl = {};

    #pragma unroll 2
    for (int cn = 0; cn < 8; ++cn) {
        const int j0 = cn * 256 + w * 32 + kg * 8;

        // mask byte: bits e=0..7 <-> j0+e  (flat byte = row*256 + j/8)
        const unsigned int mb = mb8[iloc * 256 + cn * 32 + w * 4 + kg];

        float4 w0 = *(const float4*)(wh2b + j0);
        float4 w1 = *(const float4*)(wh2b + j0 + 4);

        bf16x8 bf[4];
        #pragma unroll
        for (int ft = 0; ft < 4; ++ft)
            bf[ft] = *(const bf16x8*)(whTb + (size_t)(ft * 16 + iloc) * NN + j0);

        float pv[8];
        {
            float e, pe;
            e = wh1v + w0.x; pe = __expf(fmaxf(e, 0.2f*e)); pv[0] = (mb & 1u)   ? pe : 0.f;
            e = wh1v + w0.y; pe = __expf(fmaxf(e, 0.2f*e)); pv[1] = (mb & 2u)   ? pe : 0.f;
            e = wh1v + w0.z; pe = __expf(fmaxf(e, 0.2f*e)); pv[2] = (mb & 4u)   ? pe : 0.f;
            e = wh1v + w0.w; pe = __expf(fmaxf(e, 0.2f*e)); pv[3] = (mb & 8u)   ? pe : 0.f;
            e = wh1v + w1.x; pe = __expf(fmaxf(e, 0.2f*e)); pv[4] = (mb & 16u)  ? pe : 0.f;
            e = wh1v + w1.y; pe = __expf(fmaxf(e, 0.2f*e)); pv[5] = (mb & 32u)  ? pe : 0.f;
            e = wh1v + w1.z; pe = __expf(fmaxf(e, 0.2f*e)); pv[6] = (mb & 64u)  ? pe : 0.f;
            e = wh1v + w1.w; pe = __expf(fmaxf(e, 0.2f*e)); pv[7] = (mb & 128u) ? pe : 0.f;
        }
        bf16x8 af;
        #pragma unroll
        for (int e = 0; e < 8; ++e) af[e] = f2bf(pv[e]);

        accl = __builtin_amdgcn_mfma_f32_16x16x32_bf16(af, onesf, accl, 0, 0, 0);
        #pragma unroll
        for (int ft = 0; ft < 4; ++ft)
            acc[ft] = __builtin_amdgcn_mfma_f32_16x16x32_bf16(af, bf[ft], acc[ft], 0, 0, 0);
    }

    // stash partials using the MEASURED layout maps
    #pragma unroll
    for (int ft = 0; ft < 4; ++ft)
        #pragma unroll
        for (int reg = 0; reg < 4; ++reg)
            lds_acc[w][rmap[reg]][ft * 16 + cmap[reg]] = acc[ft][reg];
    #pragma unroll
    for (int reg = 0; reg < 4; ++reg)
        if (cmap[reg] == 0) lds_l[w][rmap[reg]] = accl[reg];
    __syncthreads();

    // combine across 8 waves + normalize + elu; thread -> (f, 2 rows)
    const int f  = tid & 63;
    const int rh = tid >> 6;                 // 0..7
    #pragma unroll
    for (int rr = 0; rr < 2; ++rr) {
        const int r = rh * 2 + rr;
        float s = 0.f, l = 0.f;
        #pragma unroll
        for (int ww = 0; ww < 8; ++ww) {
            s += lds_acc[ww][r][f];
            l += lds_l[ww][r];
        }
        float v = s / l;
        out[(size_t)(row0 + r) * FOUT + f] = (v > 0.f) ? v : (__expf(v) - 1.f);
    }
}

// ---------------------------------------------------------------------------
extern "C" void kernel_launch(void* const* d_in, const int* in_sizes, int n_in,
                              void* d_out, int out_size, void* d_ws, size_t ws_size,
                              hipStream_t stream) {
    const float* h   = (const float*)d_in[0];   // [8,2048,128]
    const float* adj = (const float*)d_in[1];   // [8,2048,2048]
    const float* W   = (const float*)d_in[2];   // [128,64]
    const float* a   = (const float*)d_in[3];   // [128,1]
    float* out = (float*)d_out;                 // [8,2048,64]

    short* whT = (short*)d_ws;                              // 2 MB bf16 [8][64][2048]
    float* wh1 = (float*)(whT + (size_t)BATCH * FOUT * NN); // 64 KB
    float* wh2 = wh1 + ROWS_TOTAL;                          // 64 KB
    unsigned char* maskb = (unsigned char*)(wh2 + ROWS_TOTAL);  // 4 MB

    k01<<<K0_BLOCKS + K1_BLOCKS, 256, 0, stream>>>(h, W, a, adj, whT, wh1, wh2, maskb);
    k2_attn<<<ROWS_TOTAL / 16, 512, 0, stream>>>((const unsigned long long*)maskb,
                                                 whT, wh1, wh2, out);
}

// Round 12
// 72.303 us; speedup vs baseline: 1.3635x; 1.3635x over previous
//
#include <hip/hip_runtime.h>
#include <hip/hip_bf16.h>

#define BATCH 8
#define NN 2048
#define FIN 128
#define FOUT 64
#define ROWS_TOTAL (BATCH * NN)           // 16384
#define K1_BLOCKS 512                     // projection blocks (dispatched first)
#define K0_BLOCKS 2048                    // mask blocks
#define K0_THREADS (K0_BLOCKS * 256)      // 524288

typedef __attribute__((ext_vector_type(8))) short bf16x8;
typedef __attribute__((ext_vector_type(4))) float f32x4;
typedef __attribute__((ext_vector_type(8))) short short8;

__device__ inline short f2bf(float x) {
    __hip_bfloat16 b = __float2bfloat16(x);   // RNE
    short s;
    __builtin_memcpy(&s, &b, 2);
    return s;
}

// ---------------------------------------------------------------------------
// K01: projection (blocks [0,512)) + adj->bitmask (blocks [512,2560)).
// k1 body byte-identical to validated rounds 1..11; placed FIRST so its ~6us
// hides under the adj stream.
// k0: R9's pair layout (thread t owns float4s {2g, 2g+1}, g = it*524288+T),
// but with a LIVENESS PIN (empty asm consuming all 16 results) so the
// register allocator must keep 256 B/thread truly in flight — R9/R11 showed
// VGPR_Count=52, i.e. the depth was silently serialized away.
// ---------------------------------------------------------------------------
__global__ __launch_bounds__(256) void k01(
        const float* __restrict__ h, const float* __restrict__ W,
        const float* __restrict__ a, const float* __restrict__ adj,
        short* __restrict__ whT, float* __restrict__ wh1, float* __restrict__ wh2,
        unsigned char* __restrict__ maskb) {
    const int tid  = threadIdx.x;
    const int lane = tid & 63;
    const int wid  = tid >> 6;

    if (blockIdx.x >= K1_BLOCKS) {
        // ---------------- k0: adj -> bitmask, forced-deep stream ----------------
        const int T = (blockIdx.x - K1_BLOCKS) * 256 + tid;   // 0..524287
        const f32x4* adj4 = (const f32x4*)adj;

        f32x4 va[8], vb[8];
        #pragma unroll
        for (int it = 0; it < 8; ++it) {
            const size_t g = (size_t)it * K0_THREADS + T;     // octet/byte index
            va[it] = adj4[2 * g];
            vb[it] = adj4[2 * g + 1];
        }
        // liveness pin: all 16 results must be resident simultaneously here
        asm volatile("" ::
            "v"(va[0]), "v"(va[1]), "v"(va[2]), "v"(va[3]),
            "v"(va[4]), "v"(va[5]), "v"(va[6]), "v"(va[7]),
            "v"(vb[0]), "v"(vb[1]), "v"(vb[2]), "v"(vb[3]),
            "v"(vb[4]), "v"(vb[5]), "v"(vb[6]), "v"(vb[7]));

        #pragma unroll
        for (int it = 0; it < 8; ++it) {
            const size_t g = (size_t)it * K0_THREADS + T;
            unsigned int by =
                (va[it][0] == 0.f ? 1u   : 0u) | (va[it][1] == 0.f ? 2u   : 0u) |
                (va[it][2] == 0.f ? 4u   : 0u) | (va[it][3] == 0.f ? 8u   : 0u) |
                (vb[it][0] == 0.f ? 16u  : 0u) | (vb[it][1] == 0.f ? 32u  : 0u) |
                (vb[it][2] == 0.f ? 64u  : 0u) | (vb[it][3] == 0.f ? 128u : 0u);
            maskb[g] = (unsigned char)by;
        }
    } else {
        // ---------------- k1: wh = h @ W, whT bf16, wh1/wh2 ----------------
        const int gw   = blockIdx.x * 4 + wid;
        const int row0 = gw * 8;
        const int b    = row0 >> 11;
        const int rloc = row0 & (NN - 1);

        float acc[8] = {0.f,0.f,0.f,0.f,0.f,0.f,0.f,0.f};
        const float* hrow = h + (size_t)row0 * FIN;

        #pragma unroll 2
        for (int kc = 0; kc < FIN / 4; ++kc) {
            float wv0 = W[(4*kc + 0) * FOUT + lane];
            float wv1 = W[(4*kc + 1) * FOUT + lane];
            float wv2 = W[(4*kc + 2) * FOUT + lane];
            float wv3 = W[(4*kc + 3) * FOUT + lane];
            #pragma unroll
            for (int r = 0; r < 8; ++r) {
                float4 h4 = *(const float4*)(hrow + r * FIN + 4*kc);
                acc[r] = fmaf(h4.x, wv0, acc[r]);
                acc[r] = fmaf(h4.y, wv1, acc[r]);
                acc[r] = fmaf(h4.z, wv2, acc[r]);
                acc[r] = fmaf(h4.w, wv3, acc[r]);
            }
        }

        short8 st;
        #pragma unroll
        for (int r = 0; r < 8; ++r) st[r] = f2bf(acc[r]);
        *(short8*)(whT + ((size_t)b * FOUT + lane) * NN + rloc) = st;

        const float a1 = a[lane];
        const float a2 = a[FOUT + lane];
        #pragma unroll
        for (int r = 0; r < 8; ++r) {
            const int row = row0 + r;
            float v1 = acc[r] * a1;
            float v2 = acc[r] * a2;
            #pragma unroll
            for (int m = 32; m >= 1; m >>= 1) {
                v1 += __shfl_xor(v1, m, 64);
                v2 += __shfl_xor(v2, m, 64);
            }
            if (lane == 0) { wh1[row] = v1; wh2[row] = v2; }
        }
    }
}

// ---------------------------------------------------------------------------
// K2 v5 (byte-identical to validated rounds 9..11 core): mask-driven fused
// softmax+PV via MFMA, layout-self-calibrated. No adj stream, no in-loop
// barriers. 16 rows x 8 waves; wave w owns j = cn*256 + w*32 + [0,32).
// ---------------------------------------------------------------------------
__global__ __launch_bounds__(512) void k2_attn(
        const unsigned long long* __restrict__ maskg, const short* __restrict__ whT,
        const float* __restrict__ wh1, const float* __restrict__ wh2,
        float* __restrict__ out) {
    __shared__ unsigned long long lds_mask64[512];   // 4 KB: [16 rows][32 words]
    __shared__ float lds_acc[8][16][FOUT];           // 32 KB
    __shared__ float lds_l[8][16];

    const int tid  = threadIdx.x;
    const int lane = tid & 63;
    const int w    = tid >> 6;               // 0..7
    const int row0 = blockIdx.x * 16;
    const int b    = row0 >> 11;
    const int iloc = lane & 15;
    const int kg   = lane >> 4;              // 0..3

    const float* wh2b = wh2 + b * NN;
    const short* whTb = whT + (size_t)b * FOUT * NN;
    const float  wh1v = wh1[row0 + iloc];

    // mask preload: rows row0..row0+15 = 512 uint64, one per thread
    lds_mask64[tid] = maskg[(size_t)row0 * 32 + tid];

    // --- layout self-calibration (proven round 3) ---
    bf16x8 onesf, idxf;
    #pragma unroll
    for (int e = 0; e < 8; ++e) { onesf[e] = (short)0x3F80; idxf[e] = f2bf((float)iloc); }
    f32x4 rowM = {}, colM = {};
    rowM = __builtin_amdgcn_mfma_f32_16x16x32_bf16(idxf, onesf, rowM, 0, 0, 0);
    colM = __builtin_amdgcn_mfma_f32_16x16x32_bf16(onesf, idxf, colM, 0, 0, 0);
    int rmap[4], cmap[4];
    #pragma unroll
    for (int reg = 0; reg < 4; ++reg) {
        int r = (int)(rowM[reg] * 0.03125f + 0.5f);
        int c = (int)(colM[reg] * 0.03125f + 0.5f);
        rmap[reg] = min(max(r, 0), 15);
        cmap[reg] = min(max(c, 0), 15);
    }

    __syncthreads();   // mask ready
    const unsigned char* mb8 = (const unsigned char*)lds_mask64;

    f32x4 acc[4] = {};
    f32x4 accl = {};

    #pragma unroll 2
    for (int cn = 0; cn < 8; ++cn) {
        const int j0 = cn * 256 + w * 32 + kg * 8;

        // mask byte: bits e=0..7 <-> j0+e  (flat byte = row*256 + j/8)
        const unsigned int mb = mb8[iloc * 256 + cn * 32 + w * 4 + kg];

        float4 w0 = *(const float4*)(wh2b + j0);
        float4 w1 = *(const float4*)(wh2b + j0 + 4);

        bf16x8 bf[4];
        #pragma unroll
        for (int ft = 0; ft < 4; ++ft)
            bf[ft] = *(const bf16x8*)(whTb + (size_t)(ft * 16 + iloc) * NN + j0);

        float pv[8];
        {
            float e, pe;
            e = wh1v + w0.x; pe = __expf(fmaxf(e, 0.2f*e)); pv[0] = (mb & 1u)   ? pe : 0.f;
            e = wh1v + w0.y; pe = __expf(fmaxf(e, 0.2f*e)); pv[1] = (mb & 2u)   ? pe : 0.f;
            e = wh1v + w0.z; pe = __expf(fmaxf(e, 0.2f*e)); pv[2] = (mb & 4u)   ? pe : 0.f;
            e = wh1v + w0.w; pe = __expf(fmaxf(e, 0.2f*e)); pv[3] = (mb & 8u)   ? pe : 0.f;
            e = wh1v + w1.x; pe = __expf(fmaxf(e, 0.2f*e)); pv[4] = (mb & 16u)  ? pe : 0.f;
            e = wh1v + w1.y; pe = __expf(fmaxf(e, 0.2f*e)); pv[5] = (mb & 32u)  ? pe : 0.f;
            e = wh1v + w1.z; pe = __expf(fmaxf(e, 0.2f*e)); pv[6] = (mb & 64u)  ? pe : 0.f;
            e = wh1v + w1.w; pe = __expf(fmaxf(e, 0.2f*e)); pv[7] = (mb & 128u) ? pe : 0.f;
        }
        bf16x8 af;
        #pragma unroll
        for (int e = 0; e < 8; ++e) af[e] = f2bf(pv[e]);

        accl = __builtin_amdgcn_mfma_f32_16x16x32_bf16(af, onesf, accl, 0, 0, 0);
        #pragma unroll
        for (int ft = 0; ft < 4; ++ft)
            acc[ft] = __builtin_amdgcn_mfma_f32_16x16x32_bf16(af, bf[ft], acc[ft], 0, 0, 0);
    }

    // stash partials using the MEASURED layout maps
    #pragma unroll
    for (int ft = 0; ft < 4; ++ft)
        #pragma unroll
        for (int reg = 0; reg < 4; ++reg)
            lds_acc[w][rmap[reg]][ft * 16 + cmap[reg]] = acc[ft][reg];
    #pragma unroll
    for (int reg = 0; reg < 4; ++reg)
        if (cmap[reg] == 0) lds_l[w][rmap[reg]] = accl[reg];
    __syncthreads();

    // combine across 8 waves + normalize + elu; thread -> (f, 2 rows)
    const int f  = tid & 63;
    const int rh = tid >> 6;                 // 0..7
    #pragma unroll
    for (int rr = 0; rr < 2; ++rr) {
        const int r = rh * 2 + rr;
        float s = 0.f, l = 0.f;
        #pragma unroll
        for (int ww = 0; ww < 8; ++ww) {
            s += lds_acc[ww][r][f];
            l += lds_l[ww][r];
        }
        float v = s / l;
        out[(size_t)(row0 + r) * FOUT + f] = (v > 0.f) ? v : (__expf(v) - 1.f);
    }
}

// ---------------------------------------------------------------------------
extern "C" void kernel_launch(void* const* d_in, const int* in_sizes, int n_in,
                              void* d_out, int out_size, void* d_ws, size_t ws_size,
                              hipStream_t stream) {
    const float* h   = (const float*)d_in[0];   // [8,2048,128]
    const float* adj = (const float*)d_in[1];   // [8,2048,2048]
    const float* W   = (const float*)d_in[2];   // [128,64]
    const float* a   = (const float*)d_in[3];   // [128,1]
    float* out = (float*)d_out;                 // [8,2048,64]

    short* whT = (short*)d_ws;                              // 2 MB bf16 [8][64][2048]
    float* wh1 = (float*)(whT + (size_t)BATCH * FOUT * NN); // 64 KB
    float* wh2 = wh1 + ROWS_TOTAL;                          // 64 KB
    unsigned char* maskb = (unsigned char*)(wh2 + ROWS_TOTAL);  // 4 MB

    k01<<<K1_BLOCKS + K0_BLOCKS, 256, 0, stream>>>(h, W, a, adj, whT, wh1, wh2, maskb);
    k2_attn<<<ROWS_TOTAL / 16, 512, 0, stream>>>((const unsigned long long*)maskb,
                                                 whT, wh1, wh2, out);
}